// Round 10
// baseline (128.529 us; speedup 1.0000x reference)
//
#include <hip/hip_runtime.h>
#include <hip/hip_bf16.h>

typedef unsigned short u16;
typedef unsigned int u32;
typedef short bf16x8 __attribute__((ext_vector_type(8)));
typedef float f32x4 __attribute__((ext_vector_type(4)));

#define NPX 32768

__device__ __forceinline__ u16 f2bf(float f) {
  union { float f; u32 u; } v; v.f = f;
  return (u16)((v.u + 0x7FFFu + ((v.u >> 16) & 1u)) >> 16);
}

__device__ __forceinline__ void gload16(const u16* g, u16* l) {
  __builtin_amdgcn_global_load_lds(
      (const __attribute__((address_space(1))) void*)g,
      (__attribute__((address_space(3))) void*)l, 16, 0, 0);
}

// Coalesced B-operand layout: dst = kk*8192 + o*32 + lk*8 + e  (c = kk*32+lk*8+e)

// ---------------- prep kernels ----------------
__global__ __launch_bounds__(256) void prep_small(
    const float* __restrict__ wq, const float* __restrict__ wk,
    const float* __restrict__ wv, const float* __restrict__ w1,
    const float* __restrict__ wW, const float* __restrict__ gamma,
    const float* __restrict__ beta, const float* __restrict__ mean,
    const float* __restrict__ var,
    u16* __restrict__ wqb, u16* __restrict__ wkb, u16* __restrict__ wvb,
    u16* __restrict__ w1b, u16* __restrict__ wWpb, float* __restrict__ bWp) {
  int idx = blockIdx.x * 256 + threadIdx.x;
  if (idx < 65536) {
    int o = idx >> 8, c = idx & 255;
    int dst = (c >> 5) * 8192 + o * 32 + ((c >> 3) & 3) * 8 + (c & 7);
    wqb[dst] = f2bf(wq[idx]);
    wkb[dst] = f2bf(wk[idx]);
    wvb[dst] = f2bf(wv[idx]);
    w1b[dst] = f2bf(w1[idx]);
  } else if (idx < 65536 + 16384) {
    int j = idx - 65536;
    int o = j >> 6, c = j & 63;
    float inv = gamma[o] * rsqrtf(var[o] + 1e-5f);
    int dst = (c >> 5) * 8192 + o * 32 + ((c >> 3) & 3) * 8 + (c & 7);
    wWpb[dst] = f2bf(wW[j] * inv);
  } else if (idx < 65536 + 16384 + 256) {
    int o = idx - 65536 - 16384;
    float inv = gamma[o] * rsqrtf(var[o] + 1e-5f);
    bWp[o] = beta[o] - mean[o] * inv;
  }
}

// w3 [o][c][3][3] f32 -> w3c slab s = cb32*9 + tap, each [256o][4lk][8e] (8192 u16)
__global__ __launch_bounds__(256) void prep_w3t(const float* __restrict__ w3,
                                                u16* __restrict__ w3c) {
  int idx = blockIdx.x * 256 + threadIdx.x;  // o*512+c, 131072 total
  int o = idx >> 9, c = idx & 511;
  int cb = c >> 5;
  int lk = (c >> 3) & 3, e = c & 7;
  #pragma unroll
  for (int t = 0; t < 9; ++t)
    w3c[(size_t)(cb * 9 + t) * 8192 + o * 32 + lk * 8 + e] =
        f2bf(w3[idx * 9 + t]);
}

// ---------------- pass 1: NCHW->NHWC transpose (fused) + QKV + attention + W + BN ----------------
__global__ __launch_bounds__(256, 2) void attn_kernel(
    const float* __restrict__ qsrc, const float* __restrict__ ksrc,
    u16* __restrict__ xcat,
    const u16* __restrict__ wqb, const u16* __restrict__ wkb, const u16* __restrict__ wvb,
    const float* __restrict__ bq, const float* __restrict__ bk, const float* __restrict__ bv,
    const u16* __restrict__ wWpb, const float* __restrict__ bWp) {
  __shared__ __align__(16) char smem[74752];
  u16* aq = (u16*)smem;                    // [64][256] swizzled, 32KB
  u16* ak = (u16*)(smem + 32768);          // [64][256] swizzled, 32KB
  u16* tile = (u16*)(smem + 65536);        // [64][72] transpose tile, 9216B
  float* att_s = (float*)(smem + 65536);   // [4][64] (after tile is dead)
  u16* wsum = (u16*)(smem + 66560);        // [64][64] swizzled, 8KB
  float* wbuf = (float*)smem;              // [4][64][64] f32, reuses aq/ak
  u16* ob = (u16*)smem;                    // [64][264] out stage, reuses aq/ak

  int tid = threadIdx.x;
  int lane = tid & 63, wv_ = tid >> 6;
  int lc = lane & 15, lk = lane >> 4;
  int px0 = blockIdx.x * 64;
  int b = px0 >> 12, hw0 = px0 & 4095;

  // ---- fused transpose: 8 rounds (Q cc=0..3, K cc=0..3) ----
  #pragma unroll
  for (int t = 0; t < 8; ++t) {
    const float* src = (t < 4) ? qsrc : ksrc;
    int cc = t & 3;
    #pragma unroll
    for (int i = 0; i < 4; ++i) {
      int idx = tid + 256 * i;
      int c = idx >> 4, p4 = idx & 15;
      const float4 v = *(const float4*)&src[(size_t)(b * 256 + cc * 64 + c) * 4096 + hw0 + p4 * 4];
      u32 lo = f2bf(v.x) | ((u32)f2bf(v.y) << 16);
      u32 hi = f2bf(v.z) | ((u32)f2bf(v.w) << 16);
      *(uint2*)&tile[c * 72 + p4 * 4] = make_uint2(lo, hi);
    }
    __syncthreads();
    int px = tid >> 2, cq = tid & 3;
    u32 vv[8];
    #pragma unroll
    for (int i = 0; i < 8; ++i) {
      u16 a = tile[(cq * 16 + 2 * i) * 72 + px];
      u16 bb = tile[(cq * 16 + 2 * i + 1) * 72 + px];
      vv[i] = a | ((u32)bb << 16);
    }
    u16* dstl = (t < 4) ? aq : ak;
    int c8 = cc * 8 + cq * 2;
    *(uint4*)(dstl + px * 256 + (c8 ^ (px & 7)) * 8) = make_uint4(vv[0], vv[1], vv[2], vv[3]);
    *(uint4*)(dstl + px * 256 + ((c8 + 1) ^ (px & 7)) * 8) = make_uint4(vv[4], vv[5], vv[6], vv[7]);
    if (t >= 4) {  // key: also write linear bf16 into xcat[px][0..255]
      u16* dp = xcat + (size_t)(px0 + px) * 512 + cc * 64 + cq * 16;
      *(uint4*)dp = make_uint4(vv[0], vv[1], vv[2], vv[3]);
      *(uint4*)(dp + 8) = make_uint4(vv[4], vv[5], vv[6], vv[7]);
    }
    __syncthreads();
  }

  f32x4 zero4 = {0.f, 0.f, 0.f, 0.f};
  f32x4 accq[4][4], acck[4][4];
  #pragma unroll
  for (int mi = 0; mi < 4; ++mi)
    #pragma unroll
    for (int nj = 0; nj < 4; ++nj) { accq[mi][nj] = zero4; acck[mi][nj] = zero4; }

  // Q = aq x wqb, K = ak x wkb  (K=256, B coalesced: kk*8192 + n*32 + lk*8)
  #pragma unroll
  for (int kk = 0; kk < 8; ++kk) {
    bf16x8 afq[4], afk[4], bfq[4], bfk[4];
    #pragma unroll
    for (int mi = 0; mi < 4; ++mi) {
      int px = mi * 16 + lc;
      int s = (kk * 4 + lk) ^ (px & 7);
      afq[mi] = *(const bf16x8*)(aq + px * 256 + s * 8);
      afk[mi] = *(const bf16x8*)(ak + px * 256 + s * 8);
    }
    #pragma unroll
    for (int nj = 0; nj < 4; ++nj) {
      int n = wv_ * 64 + nj * 16 + lc;
      bfq[nj] = *(const bf16x8*)(wqb + kk * 8192 + n * 32 + lk * 8);
      bfk[nj] = *(const bf16x8*)(wkb + kk * 8192 + n * 32 + lk * 8);
    }
    #pragma unroll
    for (int mi = 0; mi < 4; ++mi)
      #pragma unroll
      for (int nj = 0; nj < 4; ++nj) {
        accq[mi][nj] = __builtin_amdgcn_mfma_f32_16x16x32_bf16(afq[mi], bfq[nj], accq[mi][nj], 0, 0, 0);
        acck[mi][nj] = __builtin_amdgcn_mfma_f32_16x16x32_bf16(afk[mi], bfk[nj], acck[mi][nj], 0, 0, 0);
      }
  }

  #pragma unroll
  for (int nj = 0; nj < 4; ++nj) {
    float bqv = bq[wv_ * 64 + nj * 16 + lc];
    float bkv = bk[wv_ * 64 + nj * 16 + lc];
    #pragma unroll
    for (int mi = 0; mi < 4; ++mi)
      #pragma unroll
      for (int j = 0; j < 4; ++j) { accq[mi][nj][j] += bqv; acck[mi][nj][j] += bkv; }
  }

  // attention scores for own head (wave == head); reduce over the 16 col-lanes
  float smx[4][4];
  #pragma unroll
  for (int mi = 0; mi < 4; ++mi)
    #pragma unroll
    for (int j = 0; j < 4; ++j) {
      float p = 0.f;
      #pragma unroll
      for (int nj = 0; nj < 4; ++nj) p += accq[mi][nj][j] * acck[mi][nj][j];
      p += __shfl_xor(p, 1);
      p += __shfl_xor(p, 2);
      p += __shfl_xor(p, 4);
      p += __shfl_xor(p, 8);
      float a = p * 0.0625f;  // / sqrt(256)
      smx[mi][j] = a;
      if (lc == 0) att_s[wv_ * 64 + mi * 16 + lk * 4 + j] = a;
    }
  __syncthreads();
  // softmax over 4 heads
  #pragma unroll
  for (int mi = 0; mi < 4; ++mi)
    #pragma unroll
    for (int j = 0; j < 4; ++j) {
      int px = mi * 16 + lk * 4 + j;
      float a0 = att_s[px], a1 = att_s[64 + px], a2 = att_s[128 + px], a3 = att_s[192 + px];
      float mx = fmaxf(fmaxf(a0, a1), fmaxf(a2, a3));
      float e0 = __expf(a0 - mx), e1 = __expf(a1 - mx);
      float e2 = __expf(a2 - mx), e3 = __expf(a3 - mx);
      float den = e0 + e1 + e2 + e3;
      float ew = wv_ == 0 ? e0 : (wv_ == 1 ? e1 : (wv_ == 2 ? e2 : e3));
      smx[mi][j] = ew / den;
    }

  // V projection
  f32x4 accv[4][4];
  #pragma unroll
  for (int mi = 0; mi < 4; ++mi)
    #pragma unroll
    for (int nj = 0; nj < 4; ++nj) accv[mi][nj] = zero4;
  #pragma unroll
  for (int kk = 0; kk < 8; ++kk) {
    bf16x8 af[4], bfr[4];
    #pragma unroll
    for (int mi = 0; mi < 4; ++mi) {
      int px = mi * 16 + lc;
      int s = (kk * 4 + lk) ^ (px & 7);
      af[mi] = *(const bf16x8*)(ak + px * 256 + s * 8);
    }
    #pragma unroll
    for (int nj = 0; nj < 4; ++nj) {
      int n = wv_ * 64 + nj * 16 + lc;
      bfr[nj] = *(const bf16x8*)(wvb + kk * 8192 + n * 32 + lk * 8);
    }
    #pragma unroll
    for (int mi = 0; mi < 4; ++mi)
      #pragma unroll
      for (int nj = 0; nj < 4; ++nj)
        accv[mi][nj] = __builtin_amdgcn_mfma_f32_16x16x32_bf16(af[mi], bfr[nj], accv[mi][nj], 0, 0, 0);
  }
  #pragma unroll
  for (int nj = 0; nj < 4; ++nj) {
    float bvv = bv[wv_ * 64 + nj * 16 + lc];
    #pragma unroll
    for (int mi = 0; mi < 4; ++mi)
      #pragma unroll
      for (int j = 0; j < 4; ++j) accv[mi][nj][j] += bvv;
  }
  __syncthreads();  // all waves done reading aq/ak -> reuse as wbuf

  #pragma unroll
  for (int mi = 0; mi < 4; ++mi)
    #pragma unroll
    for (int nj = 0; nj < 4; ++nj)
      #pragma unroll
      for (int j = 0; j < 4; ++j) {
        int px = mi * 16 + lk * 4 + j;
        wbuf[(wv_ * 64 + px) * 64 + nj * 16 + lc] = smx[mi][j] * accv[mi][nj][j];
      }
  __syncthreads();

  // sum heads -> weighted [64px][64d] bf16 (swizzled)
  #pragma unroll
  for (int i = 0; i < 2; ++i) {
    int idx = tid + 256 * i;
    int px = idx >> 3, c = idx & 7;
    float a8[8] = {0.f, 0.f, 0.f, 0.f, 0.f, 0.f, 0.f, 0.f};
    #pragma unroll
    for (int h = 0; h < 4; ++h) {
      const float4* p = (const float4*)(wbuf + ((h * 64 + px) * 64 + c * 8));
      float4 u0 = p[0], u1 = p[1];
      a8[0] += u0.x; a8[1] += u0.y; a8[2] += u0.z; a8[3] += u0.w;
      a8[4] += u1.x; a8[5] += u1.y; a8[6] += u1.z; a8[7] += u1.w;
    }
    u32 p0 = f2bf(a8[0]) | ((u32)f2bf(a8[1]) << 16);
    u32 p1 = f2bf(a8[2]) | ((u32)f2bf(a8[3]) << 16);
    u32 p2 = f2bf(a8[4]) | ((u32)f2bf(a8[5]) << 16);
    u32 p3 = f2bf(a8[6]) | ((u32)f2bf(a8[7]) << 16);
    *(uint4*)(wsum + px * 64 + (c ^ (px & 7)) * 8) = make_uint4(p0, p1, p2, p3);
  }
  __syncthreads();

  // out = weighted x wW'^T + bWp  (K=64)
  f32x4 a4[4][4];
  #pragma unroll
  for (int mi = 0; mi < 4; ++mi)
    #pragma unroll
    for (int nj = 0; nj < 4; ++nj) a4[mi][nj] = zero4;
  #pragma unroll
  for (int kk = 0; kk < 2; ++kk) {
    bf16x8 af[4], bfr[4];
    #pragma unroll
    for (int mi = 0; mi < 4; ++mi) {
      int px = mi * 16 + lc;
      int s = (kk * 4 + lk) ^ (px & 7);
      af[mi] = *(const bf16x8*)(wsum + px * 64 + s * 8);
    }
    #pragma unroll
    for (int nj = 0; nj < 4; ++nj) {
      int n = wv_ * 64 + nj * 16 + lc;
      bfr[nj] = *(const bf16x8*)(wWpb + kk * 8192 + n * 32 + lk * 8);
    }
    #pragma unroll
    for (int mi = 0; mi < 4; ++mi)
      #pragma unroll
      for (int nj = 0; nj < 4; ++nj)
        a4[mi][nj] = __builtin_amdgcn_mfma_f32_16x16x32_bf16(af[mi], bfr[nj], a4[mi][nj], 0, 0, 0);
  }
  // stage out through LDS (ob, [64][264]) then coalesced 16B stores
  #pragma unroll
  for (int nj = 0; nj < 4; ++nj) {
    int o = wv_ * 64 + nj * 16 + lc;
    float bb = bWp[o];
    #pragma unroll
    for (int mi = 0; mi < 4; ++mi)
      #pragma unroll
      for (int j = 0; j < 4; ++j) {
        int px = mi * 16 + lk * 4 + j;
        ob[px * 264 + o] = f2bf(a4[mi][nj][j] + bb);
      }
  }
  __syncthreads();
  #pragma unroll
  for (int i = 0; i < 8; ++i) {
    int idx = tid + 256 * i;
    int px = idx >> 5, c8 = idx & 31;
    *(uint4*)(xcat + (size_t)(px0 + px) * 512 + 256 + c8 * 8) =
        *(const uint4*)(ob + px * 264 + c8 * 8);
  }
}

// ---------------- pass 2: reflect-pad 3x3 conv (512->256) + ELU + fused final 1x1 ----------------
// W-in-registers pipeline: per tap each wave needs only 4 B-frags (1KB coalesced
// L2 bursts) -> 3-slot register ring, prefetched 3 taps ahead (compiler-counted
// vmcnt). No W LDS at all; barriers only at cb boundaries (16 total). x tile in
// conflict-free slot-minor layout: chunk=(row*68+px)*4+slot -> af reads are 64
// consecutive chunks (1024 contiguous B). M=128, N=256, grid 256, 8 waves 2Mx4N.
__global__ __launch_bounds__(512) void conv3_kernel(
    const u16* __restrict__ xcat, const u16* __restrict__ w3c,
    const float* __restrict__ b3, const u16* __restrict__ w1b,
    const float* __restrict__ b1, float* __restrict__ out) {
  __shared__ __align__(16) u16 smem[33792];  // xb dbuf (2x8704 u16) / eb[128][264]
  u16* xb0 = smem;
  u16* xb1 = smem + 8704;

  int tid = threadIdx.x;
  int lane = tid & 63, wave = tid >> 6;
  int lc = lane & 15, lk = lane >> 4;
  int wr = wave >> 2, wc = wave & 3;
  int sbid = (blockIdx.x & 7) * 32 + (blockIdx.x >> 3);  // XCD-chunked, bijective
  int b = sbid >> 5, r0 = (sbid & 31) * 2;

  // x chunk decode: c -> q=c>>2, slot=c&3, row=q/68, px=q%68 (66,67 pad)
  int gx0, gx1, gx2;
  #pragma unroll
  for (int i = 0; i < 3; ++i) {
    int c = (i == 0) ? tid : (i == 1 ? tid + 512 : 1024 + lane);
    int q = c >> 2, slot = c & 3;
    int row = q / 68, px = q - row * 68;
    px = px < 66 ? px : 65;
    int h_in = r0 - 1 + row; h_in = h_in < 0 ? 1 : (h_in > 63 ? 62 : h_in);
    int w_in = px - 1;       w_in = w_in < 0 ? 1 : (w_in > 63 ? 62 : w_in);
    int g = ((b * 64 + h_in) * 64 + w_in) * 512 + slot * 8;
    if (i == 0) gx0 = g; else if (i == 1) gx1 = g; else gx2 = g;
  }
  // W per-lane offsets within a slab (u16 units); nj stride = 512
  int wo0 = ((wc * 64 + lc) * 4 + lk) * 8;

#define STAGE_X(dst, cb_)                                                       \
  do {                                                                          \
    asm volatile("" ::: "memory");                                              \
    gload16(xcat + gx0 + (cb_) * 32, (dst) + (size_t)tid * 8);                  \
    gload16(xcat + gx1 + (cb_) * 32, (dst) + (size_t)(tid + 512) * 8);          \
    gload16(xcat + gx2 + (cb_) * 32, (dst) + (size_t)(1024 + lane) * 8);        \
    asm volatile("" ::: "memory");                                              \
  } while (0)

#define PREF_W(SLOT, SLAB)                                                      \
  do {                                                                          \
    const u16* ws_ = w3c + (size_t)(SLAB) * 8192 + wo0;                         \
    Wr[SLOT][0] = *(const bf16x8*)(ws_);                                        \
    Wr[SLOT][1] = *(const bf16x8*)(ws_ + 512);                                  \
    Wr[SLOT][2] = *(const bf16x8*)(ws_ + 1024);                                 \
    Wr[SLOT][3] = *(const bf16x8*)(ws_ + 1536);                                 \
  } while (0)

  f32x4 zero4 = {0.f, 0.f, 0.f, 0.f};
  f32x4 acc[4][4];
  #pragma unroll
  for (int mi = 0; mi < 4; ++mi)
    #pragma unroll
    for (int nj = 0; nj < 4; ++nj) acc[mi][nj] = zero4;

  bf16x8 Wr[3][4];

  // prologue: X(0) then W slabs 0..2; wait X landed (12 W still flying)
  STAGE_X(xb0, 0);
  PREF_W(0, 0);
  PREF_W(1, 1);
  PREF_W(2, 2);
  asm volatile("s_waitcnt vmcnt(12)\n\ts_barrier" ::: "memory");

  for (int cb = 0; cb < 16; ++cb) {
    const u16* xcur = (cb & 1) ? xb1 : xb0;
    u16* xnxt = (cb & 1) ? xb0 : xb1;
#define TAP(T)                                                                  \
    {                                                                           \
      const int dy = (T) / 3, dx = (T) % 3;                                     \
      bf16x8 af[4];                                                             \
      _Pragma("unroll") for (int mi = 0; mi < 4; ++mi)                          \
        af[mi] = *(const bf16x8*)(xcur +                                        \
            (size_t)(((wr + dy) * 68 + mi * 16 + lc + dx) * 4 + lk) * 8);       \
      __builtin_amdgcn_s_setprio(1);                                            \
      _Pragma("unroll") for (int mi = 0; mi < 4; ++mi)                          \
        _Pragma("unroll") for (int nj = 0; nj < 4; ++nj)                        \
          acc[mi][nj] = __builtin_amdgcn_mfma_f32_16x16x32_bf16(                \
              af[mi], Wr[(T) % 3][nj], acc[mi][nj], 0, 0, 0);                   \
      __builtin_amdgcn_s_setprio(0);                                            \
      int slab_ = cb * 9 + (T) + 3;                                             \
      if (slab_ < 144) PREF_W((T) % 3, slab_);                                  \
      if ((T) == 5 && cb < 15) STAGE_X(xnxt, cb + 1);                           \
    }
    TAP(0) TAP(1) TAP(2) TAP(3) TAP(4) TAP(5) TAP(6) TAP(7) TAP(8)
#undef TAP
    if (cb < 15)
      asm volatile("s_waitcnt vmcnt(12)\n\ts_barrier" ::: "memory");
  }
#undef STAGE_X
#undef PREF_W

  __syncthreads();  // all waves done with xb before eb overwrite

  // ===== epilogue: bias + ELU -> eb[128][264], then fused final 1x1 (K=256) =====
  u16* eb = smem;
  #pragma unroll
  for (int nj = 0; nj < 4; ++nj) {
    int o = wc * 64 + nj * 16 + lc;
    float bias = b3[o];
    #pragma unroll
    for (int mi = 0; mi < 4; ++mi)
      #pragma unroll
      for (int j = 0; j < 4; ++j) {
        int p = wr * 64 + mi * 16 + lk * 4 + j;
        float v = acc[mi][nj][j] + bias;
        v = v > 0.f ? v : (__expf(v) - 1.f);  // ELU
        eb[p * 264 + o] = f2bf(v);
      }
  }
  __syncthreads();

  f32x4 acc2[4][4];
  #pragma unroll
  for (int mi = 0; mi < 4; ++mi)
    #pragma unroll
    for (int nj = 0; nj < 4; ++nj) acc2[mi][nj] = zero4;
  #pragma unroll
  for (int kk = 0; kk < 8; ++kk) {
    bf16x8 af[4], bfr[4];
    #pragma unroll
    for (int mi = 0; mi < 4; ++mi)
      af[mi] = *(const bf16x8*)(eb + (size_t)(wr * 64 + mi * 16 + lc) * 264 + kk * 32 + lk * 8);
    #pragma unroll
    for (int nj = 0; nj < 4; ++nj)
      bfr[nj] = *(const bf16x8*)(w1b + kk * 8192 + (wc * 64 + nj * 16 + lc) * 32 + lk * 8);
    #pragma unroll
    for (int mi = 0; mi < 4; ++mi)
      #pragma unroll
      for (int nj = 0; nj < 4; ++nj)
        acc2[mi][nj] = __builtin_amdgcn_mfma_f32_16x16x32_bf16(af[mi], bfr[nj], acc2[mi][nj], 0, 0, 0);
  }
  // write f32 NCHW: wave wr owns row r0+wr
  #pragma unroll
  for (int nj = 0; nj < 4; ++nj) {
    int o = wc * 64 + nj * 16 + lc;
    float bias = b1[o];
    #pragma unroll
    for (int mi = 0; mi < 4; ++mi) {
      float4 v;
      v.x = acc2[mi][nj][0] + bias;
      v.y = acc2[mi][nj][1] + bias;
      v.z = acc2[mi][nj][2] + bias;
      v.w = acc2[mi][nj][3] + bias;
      *(float4*)&out[(size_t)(b * 256 + o) * 4096 + (r0 + wr) * 64 + mi * 16 + lk * 4] = v;
    }
  }
}

extern "C" void kernel_launch(void* const* d_in, const int* in_sizes, int n_in,
                              void* d_out, int out_size, void* d_ws, size_t ws_size,
                              hipStream_t stream) {
  const float* key   = (const float*)d_in[0];
  const float* query = (const float*)d_in[1];
  const float* wq    = (const float*)d_in[2];
  const float* bq    = (const float*)d_in[3];
  const float* wk    = (const float*)d_in[4];
  const float* bk    = (const float*)d_in[5];
  const float* wv    = (const float*)d_in[6];
  const float* bv    = (const float*)d_in[7];
  const float* wW    = (const float*)d_in[8];
  const float* gamma = (const float*)d_in[9];
  const float* beta  = (const float*)d_in[10];
  const float* mean  = (const float*)d_in[11];
  const float* var   = (const float*)d_in[12];
  const float* w3    = (const float*)d_in[13];
  const float* b3    = (const float*)d_in[14];
  const float* w1    = (const float*)d_in[15];
  const float* b1    = (const float*)d_in[16];
  float* out = (float*)d_out;

  char* ws = (char*)d_ws;
  u16* xcat  = (u16*)(ws + 16777216);         // 33,554,432 B  [NPX][512] bf16 (key | attn out)
  u16* w3t   = (u16*)(ws + 67108864);         //  2,359,296 B  [144 slabs][256o][4][8] bf16
  u16* wqb   = (u16*)(ws + 69468160);         //    131,072 B
  u16* wkb   = (u16*)(ws + 69599232);
  u16* wvb   = (u16*)(ws + 69730304);
  u16* w1b   = (u16*)(ws + 69861376);
  u16* wWpb  = (u16*)(ws + 69992448);         //     32,768 B
  float* bWp = (float*)(ws + 70025216);       //      1,024 B

  prep_small<<<321, 256, 0, stream>>>(wq, wk, wv, w1, wW, gamma, beta, mean, var,
                                      wqb, wkb, wvb, w1b, wWpb, bWp);
  prep_w3t<<<512, 256, 0, stream>>>(w3, w3t);
  attn_kernel<<<512, 256, 0, stream>>>(query, key, xcat, wqb, wkb, wvb,
                                       bq, bk, bv, wWpb, bWp);
  conv3_kernel<<<256, 512, 0, stream>>>(xcat, w3t, b3, w1b, b1, out);
}

// Round 11
// 117.865 us; speedup vs baseline: 1.0905x; 1.0905x over previous
//
#include <hip/hip_runtime.h>
#include <hip/hip_bf16.h>

typedef unsigned short u16;
typedef unsigned int u32;
typedef short bf16x8 __attribute__((ext_vector_type(8)));
typedef float f32x4 __attribute__((ext_vector_type(4)));

#define NPX 32768

__device__ __forceinline__ u16 f2bf(float f) {
  union { float f; u32 u; } v; v.f = f;
  return (u16)((v.u + 0x7FFFu + ((v.u >> 16) & 1u)) >> 16);
}

__device__ __forceinline__ void gload16(const u16* g, u16* l) {
  __builtin_amdgcn_global_load_lds(
      (const __attribute__((address_space(1))) void*)g,
      (__attribute__((address_space(3))) void*)l, 16, 0, 0);
}

// ---------------- prep kernels ----------------
__global__ __launch_bounds__(256) void prep_small(
    const float* __restrict__ wq, const float* __restrict__ wk,
    const float* __restrict__ wv, const float* __restrict__ w1,
    const float* __restrict__ wW, const float* __restrict__ gamma,
    const float* __restrict__ beta, const float* __restrict__ mean,
    const float* __restrict__ var,
    u16* __restrict__ wqb, u16* __restrict__ wkb, u16* __restrict__ wvb,
    u16* __restrict__ w1b, u16* __restrict__ wWpb, float* __restrict__ bWp) {
  int idx = blockIdx.x * 256 + threadIdx.x;
  if (idx < 65536) {
    int o = idx >> 8, c = idx & 255;
    int dst = (c >> 5) * 8192 + o * 32 + ((c >> 3) & 3) * 8 + (c & 7);
    wqb[dst] = f2bf(wq[idx]);
    wkb[dst] = f2bf(wk[idx]);
    wvb[dst] = f2bf(wv[idx]);
    w1b[dst] = f2bf(w1[idx]);
  } else if (idx < 65536 + 16384) {
    int j = idx - 65536;
    int o = j >> 6, c = j & 63;
    float inv = gamma[o] * rsqrtf(var[o] + 1e-5f);
    int dst = (c >> 5) * 8192 + o * 32 + ((c >> 3) & 3) * 8 + (c & 7);
    wWpb[dst] = f2bf(wW[j] * inv);
  } else if (idx < 65536 + 16384 + 256) {
    int o = idx - 65536 - 16384;
    float inv = gamma[o] * rsqrtf(var[o] + 1e-5f);
    bWp[o] = beta[o] - mean[o] * inv;
  }
}

// w3 [o][c][3][3] f32 -> w3c slab s = cb32*9 + tap, each [256o][4lk][8e] (8192 u16)
__global__ __launch_bounds__(256) void prep_w3t(const float* __restrict__ w3,
                                                u16* __restrict__ w3c) {
  int idx = blockIdx.x * 256 + threadIdx.x;  // o*512+c, 131072 total
  int o = idx >> 9, c = idx & 511;
  int cb = c >> 5;
  int lk = (c >> 3) & 3, e = c & 7;
  #pragma unroll
  for (int t = 0; t < 9; ++t)
    w3c[(size_t)(cb * 9 + t) * 8192 + o * 32 + lk * 8 + e] =
        f2bf(w3[idx * 9 + t]);
}

// ---------------- pass 1: NCHW->NHWC transpose (fused) + QKV + attention + W + BN ----------------
__global__ __launch_bounds__(256, 2) void attn_kernel(
    const float* __restrict__ qsrc, const float* __restrict__ ksrc,
    u16* __restrict__ xcat,
    const u16* __restrict__ wqb, const u16* __restrict__ wkb, const u16* __restrict__ wvb,
    const float* __restrict__ bq, const float* __restrict__ bk, const float* __restrict__ bv,
    const u16* __restrict__ wWpb, const float* __restrict__ bWp) {
  __shared__ __align__(16) char smem[74752];
  u16* aq = (u16*)smem;                    // [64][256] swizzled, 32KB
  u16* ak = (u16*)(smem + 32768);          // [64][256] swizzled, 32KB
  u16* tile = (u16*)(smem + 65536);        // [64][72] transpose tile, 9216B
  float* att_s = (float*)(smem + 65536);   // [4][64] (after tile is dead)
  u16* wsum = (u16*)(smem + 66560);        // [64][64] swizzled, 8KB
  float* wbuf = (float*)smem;              // [4][64][64] f32, reuses aq/ak
  u16* ob = (u16*)smem;                    // [64][264] out stage, reuses aq/ak

  int tid = threadIdx.x;
  int lane = tid & 63, wv_ = tid >> 6;
  int lc = lane & 15, lk = lane >> 4;
  int px0 = blockIdx.x * 64;
  int b = px0 >> 12, hw0 = px0 & 4095;

  // ---- fused transpose: 8 rounds (Q cc=0..3, K cc=0..3) ----
  #pragma unroll
  for (int t = 0; t < 8; ++t) {
    const float* src = (t < 4) ? qsrc : ksrc;
    int cc = t & 3;
    #pragma unroll
    for (int i = 0; i < 4; ++i) {
      int idx = tid + 256 * i;
      int c = idx >> 4, p4 = idx & 15;
      const float4 v = *(const float4*)&src[(size_t)(b * 256 + cc * 64 + c) * 4096 + hw0 + p4 * 4];
      u32 lo = f2bf(v.x) | ((u32)f2bf(v.y) << 16);
      u32 hi = f2bf(v.z) | ((u32)f2bf(v.w) << 16);
      *(uint2*)&tile[c * 72 + p4 * 4] = make_uint2(lo, hi);
    }
    __syncthreads();
    int px = tid >> 2, cq = tid & 3;
    u32 vv[8];
    #pragma unroll
    for (int i = 0; i < 8; ++i) {
      u16 a = tile[(cq * 16 + 2 * i) * 72 + px];
      u16 bb = tile[(cq * 16 + 2 * i + 1) * 72 + px];
      vv[i] = a | ((u32)bb << 16);
    }
    u16* dstl = (t < 4) ? aq : ak;
    int c8 = cc * 8 + cq * 2;
    *(uint4*)(dstl + px * 256 + (c8 ^ (px & 7)) * 8) = make_uint4(vv[0], vv[1], vv[2], vv[3]);
    *(uint4*)(dstl + px * 256 + ((c8 + 1) ^ (px & 7)) * 8) = make_uint4(vv[4], vv[5], vv[6], vv[7]);
    if (t >= 4) {  // key: also write linear bf16 into xcat[px][0..255]
      u16* dp = xcat + (size_t)(px0 + px) * 512 + cc * 64 + cq * 16;
      *(uint4*)dp = make_uint4(vv[0], vv[1], vv[2], vv[3]);
      *(uint4*)(dp + 8) = make_uint4(vv[4], vv[5], vv[6], vv[7]);
    }
    __syncthreads();
  }

  f32x4 zero4 = {0.f, 0.f, 0.f, 0.f};
  f32x4 accq[4][4], acck[4][4];
  #pragma unroll
  for (int mi = 0; mi < 4; ++mi)
    #pragma unroll
    for (int nj = 0; nj < 4; ++nj) { accq[mi][nj] = zero4; acck[mi][nj] = zero4; }

  // Q = aq x wqb, K = ak x wkb  (K=256, B coalesced: kk*8192 + n*32 + lk*8)
  #pragma unroll
  for (int kk = 0; kk < 8; ++kk) {
    bf16x8 afq[4], afk[4], bfq[4], bfk[4];
    #pragma unroll
    for (int mi = 0; mi < 4; ++mi) {
      int px = mi * 16 + lc;
      int s = (kk * 4 + lk) ^ (px & 7);
      afq[mi] = *(const bf16x8*)(aq + px * 256 + s * 8);
      afk[mi] = *(const bf16x8*)(ak + px * 256 + s * 8);
    }
    #pragma unroll
    for (int nj = 0; nj < 4; ++nj) {
      int n = wv_ * 64 + nj * 16 + lc;
      bfq[nj] = *(const bf16x8*)(wqb + kk * 8192 + n * 32 + lk * 8);
      bfk[nj] = *(const bf16x8*)(wkb + kk * 8192 + n * 32 + lk * 8);
    }
    #pragma unroll
    for (int mi = 0; mi < 4; ++mi)
      #pragma unroll
      for (int nj = 0; nj < 4; ++nj) {
        accq[mi][nj] = __builtin_amdgcn_mfma_f32_16x16x32_bf16(afq[mi], bfq[nj], accq[mi][nj], 0, 0, 0);
        acck[mi][nj] = __builtin_amdgcn_mfma_f32_16x16x32_bf16(afk[mi], bfk[nj], acck[mi][nj], 0, 0, 0);
      }
  }

  #pragma unroll
  for (int nj = 0; nj < 4; ++nj) {
    float bqv = bq[wv_ * 64 + nj * 16 + lc];
    float bkv = bk[wv_ * 64 + nj * 16 + lc];
    #pragma unroll
    for (int mi = 0; mi < 4; ++mi)
      #pragma unroll
      for (int j = 0; j < 4; ++j) { accq[mi][nj][j] += bqv; acck[mi][nj][j] += bkv; }
  }

  // attention scores for own head (wave == head); reduce over the 16 col-lanes
  float smx[4][4];
  #pragma unroll
  for (int mi = 0; mi < 4; ++mi)
    #pragma unroll
    for (int j = 0; j < 4; ++j) {
      float p = 0.f;
      #pragma unroll
      for (int nj = 0; nj < 4; ++nj) p += accq[mi][nj][j] * acck[mi][nj][j];
      p += __shfl_xor(p, 1);
      p += __shfl_xor(p, 2);
      p += __shfl_xor(p, 4);
      p += __shfl_xor(p, 8);
      float a = p * 0.0625f;  // / sqrt(256)
      smx[mi][j] = a;
      if (lc == 0) att_s[wv_ * 64 + mi * 16 + lk * 4 + j] = a;
    }
  __syncthreads();
  // softmax over 4 heads
  #pragma unroll
  for (int mi = 0; mi < 4; ++mi)
    #pragma unroll
    for (int j = 0; j < 4; ++j) {
      int px = mi * 16 + lk * 4 + j;
      float a0 = att_s[px], a1 = att_s[64 + px], a2 = att_s[128 + px], a3 = att_s[192 + px];
      float mx = fmaxf(fmaxf(a0, a1), fmaxf(a2, a3));
      float e0 = __expf(a0 - mx), e1 = __expf(a1 - mx);
      float e2 = __expf(a2 - mx), e3 = __expf(a3 - mx);
      float den = e0 + e1 + e2 + e3;
      float ew = wv_ == 0 ? e0 : (wv_ == 1 ? e1 : (wv_ == 2 ? e2 : e3));
      smx[mi][j] = ew / den;
    }

  // V projection
  f32x4 accv[4][4];
  #pragma unroll
  for (int mi = 0; mi < 4; ++mi)
    #pragma unroll
    for (int nj = 0; nj < 4; ++nj) accv[mi][nj] = zero4;
  #pragma unroll
  for (int kk = 0; kk < 8; ++kk) {
    bf16x8 af[4], bfr[4];
    #pragma unroll
    for (int mi = 0; mi < 4; ++mi) {
      int px = mi * 16 + lc;
      int s = (kk * 4 + lk) ^ (px & 7);
      af[mi] = *(const bf16x8*)(ak + px * 256 + s * 8);
    }
    #pragma unroll
    for (int nj = 0; nj < 4; ++nj) {
      int n = wv_ * 64 + nj * 16 + lc;
      bfr[nj] = *(const bf16x8*)(wvb + kk * 8192 + n * 32 + lk * 8);
    }
    #pragma unroll
    for (int mi = 0; mi < 4; ++mi)
      #pragma unroll
      for (int nj = 0; nj < 4; ++nj)
        accv[mi][nj] = __builtin_amdgcn_mfma_f32_16x16x32_bf16(af[mi], bfr[nj], accv[mi][nj], 0, 0, 0);
  }
  #pragma unroll
  for (int nj = 0; nj < 4; ++nj) {
    float bvv = bv[wv_ * 64 + nj * 16 + lc];
    #pragma unroll
    for (int mi = 0; mi < 4; ++mi)
      #pragma unroll
      for (int j = 0; j < 4; ++j) accv[mi][nj][j] += bvv;
  }
  __syncthreads();  // all waves done reading aq/ak -> reuse as wbuf

  #pragma unroll
  for (int mi = 0; mi < 4; ++mi)
    #pragma unroll
    for (int nj = 0; nj < 4; ++nj)
      #pragma unroll
      for (int j = 0; j < 4; ++j) {
        int px = mi * 16 + lk * 4 + j;
        wbuf[(wv_ * 64 + px) * 64 + nj * 16 + lc] = smx[mi][j] * accv[mi][nj][j];
      }
  __syncthreads();

  // sum heads -> weighted [64px][64d] bf16 (swizzled)
  #pragma unroll
  for (int i = 0; i < 2; ++i) {
    int idx = tid + 256 * i;
    int px = idx >> 3, c = idx & 7;
    float a8[8] = {0.f, 0.f, 0.f, 0.f, 0.f, 0.f, 0.f, 0.f};
    #pragma unroll
    for (int h = 0; h < 4; ++h) {
      const float4* p = (const float4*)(wbuf + ((h * 64 + px) * 64 + c * 8));
      float4 u0 = p[0], u1 = p[1];
      a8[0] += u0.x; a8[1] += u0.y; a8[2] += u0.z; a8[3] += u0.w;
      a8[4] += u1.x; a8[5] += u1.y; a8[6] += u1.z; a8[7] += u1.w;
    }
    u32 p0 = f2bf(a8[0]) | ((u32)f2bf(a8[1]) << 16);
    u32 p1 = f2bf(a8[2]) | ((u32)f2bf(a8[3]) << 16);
    u32 p2 = f2bf(a8[4]) | ((u32)f2bf(a8[5]) << 16);
    u32 p3 = f2bf(a8[6]) | ((u32)f2bf(a8[7]) << 16);
    *(uint4*)(wsum + px * 64 + (c ^ (px & 7)) * 8) = make_uint4(p0, p1, p2, p3);
  }
  __syncthreads();

  // out = weighted x wW'^T + bWp  (K=64)
  f32x4 a4[4][4];
  #pragma unroll
  for (int mi = 0; mi < 4; ++mi)
    #pragma unroll
    for (int nj = 0; nj < 4; ++nj) a4[mi][nj] = zero4;
  #pragma unroll
  for (int kk = 0; kk < 2; ++kk) {
    bf16x8 af[4], bfr[4];
    #pragma unroll
    for (int mi = 0; mi < 4; ++mi) {
      int px = mi * 16 + lc;
      int s = (kk * 4 + lk) ^ (px & 7);
      af[mi] = *(const bf16x8*)(wsum + px * 64 + s * 8);
    }
    #pragma unroll
    for (int nj = 0; nj < 4; ++nj) {
      int n = wv_ * 64 + nj * 16 + lc;
      bfr[nj] = *(const bf16x8*)(wWpb + kk * 8192 + n * 32 + lk * 8);
    }
    #pragma unroll
    for (int mi = 0; mi < 4; ++mi)
      #pragma unroll
      for (int nj = 0; nj < 4; ++nj)
        a4[mi][nj] = __builtin_amdgcn_mfma_f32_16x16x32_bf16(af[mi], bfr[nj], a4[mi][nj], 0, 0, 0);
  }
  // stage out through LDS (ob, [64][264]) then coalesced 16B stores
  #pragma unroll
  for (int nj = 0; nj < 4; ++nj) {
    int o = wv_ * 64 + nj * 16 + lc;
    float bb = bWp[o];
    #pragma unroll
    for (int mi = 0; mi < 4; ++mi)
      #pragma unroll
      for (int j = 0; j < 4; ++j) {
        int px = mi * 16 + lk * 4 + j;
        ob[px * 264 + o] = f2bf(a4[mi][nj][j] + bb);
      }
  }
  __syncthreads();
  #pragma unroll
  for (int i = 0; i < 8; ++i) {
    int idx = tid + 256 * i;
    int px = idx >> 5, c8 = idx & 31;
    *(uint4*)(xcat + (size_t)(px0 + px) * 512 + 256 + c8 * 8) =
        *(const uint4*)(ob + px * 264 + c8 * 8);
  }
}

// ---------------- pass 2: reflect-pad 3x3 conv (512->256) + ELU + fused final 1x1 ----------------
// m201-rhythm port: 144 phases (16 cb32 x 9 taps), K=32/phase. Per phase per
// wave: 8 ds_read + 16 MFMA between paired barriers, lgkmcnt(0)+sched_barrier,
// counted vmcnt at the closing barrier (2 normal / 5 while X in flight / 0 only
// at the last two phases). W: 3-slot LDS ring, distance-2 prefetch (ring slot
// = TAP%3, compile-time since 9%3==0). X: dbuf, issued at tap4 (2-phase
// flight). Both LDS layouts <=2-way banked (XOR swizzles, pre-swizzled
// sources per rule 21). M=128, N=256, grid 256, 8 waves 2Mx4N.
__global__ __launch_bounds__(512) void conv3_kernel(
    const u16* __restrict__ xcat, const u16* __restrict__ w3c,
    const float* __restrict__ b3, const u16* __restrict__ w1b,
    const float* __restrict__ b1, float* __restrict__ out) {
  extern __shared__ __align__(16) u16 smem[];
  u16* xb0 = smem;            // 1536 chunks = 12288 u16 (1056 used + pad)
  u16* xb1 = smem + 12288;
  u16* wring = smem + 24576;  // 3 slabs x 8192 u16

  int tid = threadIdx.x;
  int lane = tid & 63, wave = tid >> 6;
  int lc = lane & 15, lk = lane >> 4;
  int wr = wave >> 2, wc = wave & 3;
  int sbid = (blockIdx.x & 7) * 32 + (blockIdx.x >> 3);  // XCD-chunked, bijective
  int b = sbid >> 5, r0 = (sbid & 31) * 2;

  // x staging: physical chunk pc (tid-linear) holds logical (row,px,slot) with
  // group-XOR: G=pc>>3, el=(pc&7)^(G&7), px=2*(G%33)+(el>>2), slot=el&3.
  int gx0, gx1, gx2;
  #pragma unroll
  for (int i = 0; i < 3; ++i) {
    int pc = tid + 512 * i;
    int pcm = pc < 1056 ? pc : pc - 1056;  // pad region duplicates (never read)
    int G = pcm >> 3;
    int el = (pcm & 7) ^ (G & 7);
    int row = G / 33, q2 = G - row * 33;
    int px = q2 * 2 + (el >> 2), slot = el & 3;
    int h_in = r0 - 1 + row; h_in = h_in < 0 ? 1 : (h_in > 63 ? 62 : h_in);
    int w_in = px - 1;       w_in = w_in < 0 ? 1 : (w_in > 63 ? 62 : w_in);
    int g = ((b * 64 + h_in) * 64 + w_in) * 512 + slot * 8;
    if (i == 0) gx0 = g; else if (i == 1) gx1 = g; else gx2 = g;
  }
  // W staging (involution pre-swizzle): physical chunk p holds logical p^((p>>3)&7)
  int gw0 = (tid ^ ((tid >> 3) & 7)) * 8;
  int pw1 = tid + 512;
  int gw1 = (pw1 ^ ((pw1 >> 3) & 7)) * 8;

#define STAGE_X(dst, cb_)                                                       \
  do {                                                                          \
    gload16(xcat + gx0 + (cb_) * 32, (dst) + (size_t)tid * 8);                  \
    gload16(xcat + gx1 + (cb_) * 32, (dst) + (size_t)(tid + 512) * 8);          \
    gload16(xcat + gx2 + (cb_) * 32, (dst) + (size_t)(tid + 1024) * 8);         \
  } while (0)

#define STAGE_W(slot_, slab_)                                                   \
  do {                                                                          \
    const u16* ws_ = w3c + (size_t)(slab_) * 8192;                              \
    u16* wd_ = wring + (size_t)(slot_) * 8192;                                  \
    gload16(ws_ + gw0, wd_ + (size_t)tid * 8);                                  \
    gload16(ws_ + gw1, wd_ + (size_t)(tid + 512) * 8);                          \
  } while (0)

  f32x4 zero4 = {0.f, 0.f, 0.f, 0.f};
  f32x4 acc[4][4];
  #pragma unroll
  for (int mi = 0; mi < 4; ++mi)
    #pragma unroll
    for (int nj = 0; nj < 4; ++nj) acc[mi][nj] = zero4;

  // phase body: reads -> stage issues -> BAR -> lgkm(0) -> 16 MFMA -> vmcnt(N) BAR
#define PH(TAP, DO_W, DO_X, WN)                                                 \
  {                                                                             \
    const int dy = (TAP) / 3, dx = (TAP) % 3;                                   \
    bf16x8 af[4], bfr[4];                                                       \
    _Pragma("unroll") for (int mi = 0; mi < 4; ++mi) {                          \
      int px = mi * 16 + lc + dx;                                               \
      int G = (wr + dy) * 33 + (px >> 1);                                       \
      int el = (px & 1) * 4 + lk;                                               \
      af[mi] = *(const bf16x8*)(xcur + (size_t)(G * 8 + (el ^ (G & 7))) * 8);   \
    }                                                                           \
    _Pragma("unroll") for (int nj = 0; nj < 4; ++nj) {                          \
      int j = (wc * 64 + nj * 16 + lc) * 4 + lk;                                \
      bfr[nj] = *(const bf16x8*)(wring + (size_t)((TAP) % 3) * 8192 +           \
                                 (size_t)(j ^ ((j >> 3) & 7)) * 8);             \
    }                                                                           \
    if (DO_W) STAGE_W(((TAP) + 2) % 3, cb * 9 + (TAP) + 2);                     \
    if (DO_X) STAGE_X(xnxt, cb + 1);                                            \
    __builtin_amdgcn_s_barrier();                                               \
    asm volatile("s_waitcnt lgkmcnt(0)" ::: "memory");                          \
    __builtin_amdgcn_sched_barrier(0);                                          \
    __builtin_amdgcn_s_setprio(1);                                              \
    _Pragma("unroll") for (int mi = 0; mi < 4; ++mi)                            \
      _Pragma("unroll") for (int nj = 0; nj < 4; ++nj)                          \
        acc[mi][nj] = __builtin_amdgcn_mfma_f32_16x16x32_bf16(                  \
            af[mi], bfr[nj], acc[mi][nj], 0, 0, 0);                             \
    __builtin_amdgcn_s_setprio(0);                                              \
    asm volatile("s_waitcnt vmcnt(" WN ")" ::: "memory");                       \
    __builtin_amdgcn_s_barrier();                                               \
  }

  // prologue: W(0)->slot0, W(1)->slot1, X(0)->xb0, full drain once
  STAGE_W(0, 0);
  STAGE_W(1, 1);
  STAGE_X(xb0, 0);
  asm volatile("s_waitcnt vmcnt(0)" ::: "memory");
  __builtin_amdgcn_s_barrier();

  for (int cb = 0; cb < 15; ++cb) {
    const u16* xcur = (cb & 1) ? xb1 : xb0;
    u16* xnxt = (cb & 1) ? xb0 : xb1;
    PH(0, 1, 0, "2") PH(1, 1, 0, "2") PH(2, 1, 0, "2") PH(3, 1, 0, "2")
    PH(4, 1, 1, "5") PH(5, 1, 0, "5")
    PH(6, 1, 0, "2") PH(7, 1, 0, "2") PH(8, 1, 0, "2")
  }
  {  // cb = 15 peeled: W stages only while slab <= 143; exact tail waits
    const int cb = 15;
    const u16* xcur = xb1;
    u16* xnxt = xb0;  // unused
    (void)xnxt;
    PH(0, 1, 0, "2") PH(1, 1, 0, "2") PH(2, 1, 0, "2") PH(3, 1, 0, "2")
    PH(4, 1, 0, "2") PH(5, 1, 0, "2") PH(6, 1, 0, "2")
    PH(7, 0, 0, "0") PH(8, 0, 0, "0")
  }
#undef PH
#undef STAGE_X
#undef STAGE_W

  // ===== epilogue: bias + ELU -> eb[128][264], then fused final 1x1 (K=256) =====
  u16* eb = smem;
  #pragma unroll
  for (int nj = 0; nj < 4; ++nj) {
    int o = wc * 64 + nj * 16 + lc;
    float bias = b3[o];
    #pragma unroll
    for (int mi = 0; mi < 4; ++mi)
      #pragma unroll
      for (int j = 0; j < 4; ++j) {
        int p = wr * 64 + mi * 16 + lk * 4 + j;
        float v = acc[mi][nj][j] + bias;
        v = v > 0.f ? v : (__expf(v) - 1.f);  // ELU
        eb[p * 264 + o] = f2bf(v);
      }
  }
  __syncthreads();

  f32x4 acc2[4][4];
  #pragma unroll
  for (int mi = 0; mi < 4; ++mi)
    #pragma unroll
    for (int nj = 0; nj < 4; ++nj) acc2[mi][nj] = zero4;
  #pragma unroll
  for (int kk = 0; kk < 8; ++kk) {
    bf16x8 af[4], bfr[4];
    #pragma unroll
    for (int mi = 0; mi < 4; ++mi)
      af[mi] = *(const bf16x8*)(eb + (size_t)(wr * 64 + mi * 16 + lc) * 264 + kk * 32 + lk * 8);
    #pragma unroll
    for (int nj = 0; nj < 4; ++nj)
      bfr[nj] = *(const bf16x8*)(w1b + kk * 8192 + (wc * 64 + nj * 16 + lc) * 32 + lk * 8);
    #pragma unroll
    for (int mi = 0; mi < 4; ++mi)
      #pragma unroll
      for (int nj = 0; nj < 4; ++nj)
        acc2[mi][nj] = __builtin_amdgcn_mfma_f32_16x16x32_bf16(af[mi], bfr[nj], acc2[mi][nj], 0, 0, 0);
  }
  // write f32 NCHW: wave wr owns row r0+wr
  #pragma unroll
  for (int nj = 0; nj < 4; ++nj) {
    int o = wc * 64 + nj * 16 + lc;
    float bias = b1[o];
    #pragma unroll
    for (int mi = 0; mi < 4; ++mi) {
      float4 v;
      v.x = acc2[mi][nj][0] + bias;
      v.y = acc2[mi][nj][1] + bias;
      v.z = acc2[mi][nj][2] + bias;
      v.w = acc2[mi][nj][3] + bias;
      *(float4*)&out[(size_t)(b * 256 + o) * 4096 + (r0 + wr) * 64 + mi * 16 + lk * 4] = v;
    }
  }
}

extern "C" void kernel_launch(void* const* d_in, const int* in_sizes, int n_in,
                              void* d_out, int out_size, void* d_ws, size_t ws_size,
                              hipStream_t stream) {
  const float* key   = (const float*)d_in[0];
  const float* query = (const float*)d_in[1];
  const float* wq    = (const float*)d_in[2];
  const float* bq    = (const float*)d_in[3];
  const float* wk    = (const float*)d_in[4];
  const float* bk    = (const float*)d_in[5];
  const float* wv    = (const float*)d_in[6];
  const float* bv    = (const float*)d_in[7];
  const float* wW    = (const float*)d_in[8];
  const float* gamma = (const float*)d_in[9];
  const float* beta  = (const float*)d_in[10];
  const float* mean  = (const float*)d_in[11];
  const float* var   = (const float*)d_in[12];
  const float* w3    = (const float*)d_in[13];
  const float* b3    = (const float*)d_in[14];
  const float* w1    = (const float*)d_in[15];
  const float* b1    = (const float*)d_in[16];
  float* out = (float*)d_out;

  char* ws = (char*)d_ws;
  u16* xcat  = (u16*)(ws + 16777216);         // 33,554,432 B  [NPX][512] bf16 (key | attn out)
  u16* w3t   = (u16*)(ws + 67108864);         //  2,359,296 B  [144 slabs][256o][4][8] bf16
  u16* wqb   = (u16*)(ws + 69468160);         //    131,072 B
  u16* wkb   = (u16*)(ws + 69599232);
  u16* wvb   = (u16*)(ws + 69730304);
  u16* w1b   = (u16*)(ws + 69861376);
  u16* wWpb  = (u16*)(ws + 69992448);         //     32,768 B
  float* bWp = (float*)(ws + 70025216);       //      1,024 B

  (void)hipFuncSetAttribute((const void*)conv3_kernel,
                            hipFuncAttributeMaxDynamicSharedMemorySize, 98304);

  prep_small<<<321, 256, 0, stream>>>(wq, wk, wv, w1, wW, gamma, beta, mean, var,
                                      wqb, wkb, wvb, w1b, wWpb, bWp);
  prep_w3t<<<512, 256, 0, stream>>>(w3, w3t);
  attn_kernel<<<512, 256, 0, stream>>>(query, key, xcat, wqb, wkb, wvb,
                                       bq, bk, bv, wWpb, bWp);
  conv3_kernel<<<256, 512, 98304, stream>>>(xcat, w3t, b3, w1b, b1, out);
}